// Round 1
// baseline (561.953 us; speedup 1.0000x reference)
//
#include <hip/hip_runtime.h>
#include <hip/hip_bf16.h>

// Problem constants (from reference)
#define Nn 1024
#define Hh 96
#define Ee 16384
#define IN_K 9       // IN_RAW-1
#define IN_STRIDE 10 // x is (N, 10), we use first 9 cols
#define NH (Nn * Hh)

__device__ __forceinline__ float sigf(float v) {
    return __builtin_amdgcn_rcpf(1.0f + __expf(-v));
}
__device__ __forceinline__ float tanhfast(float v) {
    float e = __expf(2.0f * v);
    return (e - 1.0f) * __builtin_amdgcn_rcpf(e + 1.0f);
}
__device__ __forceinline__ float leakyf(float v) {
    return v >= 0.0f ? v : 0.01f * v;
}

// Generic linear: out[n, j] = act(dot + b[j])
// wmode 0: W stored (h_out, h_in) row-major -> x @ W.T   (W[j*h_in + k])
// wmode 1: W stored (h_in, h_out) row-major -> x @ W     (W[k*h_out + j])
template <int ACT, int WMODE>
__global__ __launch_bounds__(256) void lin_kernel(
    const float* __restrict__ in, const float* __restrict__ W,
    const float* __restrict__ b, float* __restrict__ out,
    int n_rows, int h_in, int h_out, int in_stride)
{
    int idx = blockIdx.x * 256 + threadIdx.x;
    if (idx >= n_rows * h_out) return;
    int n = idx / h_out, j = idx - n * h_out;
    const float* xr = in + n * in_stride;
    float acc = b ? b[j] : 0.0f;
    if (WMODE == 0) {
        const float* wr = W + j * h_in;
        for (int k = 0; k < h_in; ++k) acc += xr[k] * wr[k];
    } else {
        for (int k = 0; k < h_in; ++k) acc += xr[k] * W[k * h_out + j];
    }
    if (ACT == 1) acc = leakyf(acc);
    out[idx] = acc;
}

__global__ __launch_bounds__(256) void zero2_kernel(float* a, int na, float* b, int nb)
{
    int i = blockIdx.x * 256 + threadIdx.x;
    if (i < na) a[i] = 0.0f;
    if (i < nb) b[i] = 0.0f;
}

// scatter-add: s[tgt[e], h] += m[src[e], h]; cnt[tgt[e]] += 1
__global__ __launch_bounds__(256) void scatter_kernel(
    const float* __restrict__ m, const int* __restrict__ ei,
    float* __restrict__ s, float* __restrict__ cnt)
{
    int idx = blockIdx.x * 256 + threadIdx.x;
    if (idx >= Ee * Hh) return;
    int e = idx / Hh, h = idx - e * Hh;
    int src = ei[e];
    int tgt = ei[Ee + e];
    atomicAdd(&s[tgt * Hh + h], m[src * Hh + h]);
    if (h == 0) atomicAdd(&cnt[tgt], 1.0f);
}

// GRU cell: per (n,h) -> 6 dot-96
__global__ __launch_bounds__(256) void gru_kernel(
    const float* __restrict__ x, const float* __restrict__ s,
    const float* __restrict__ cnt,
    const float* __restrict__ W_ih, const float* __restrict__ W_hh,
    const float* __restrict__ b_ih, const float* __restrict__ b_hh,
    float* __restrict__ xout)
{
    int idx = blockIdx.x * 256 + threadIdx.x;
    if (idx >= NH) return;
    int n = idx / Hh, h = idx - n * Hh;
    float inv = __builtin_amdgcn_rcpf(fmaxf(cnt[n], 1.0f));
    const float* xr = x + n * Hh;
    const float* sr = s + n * Hh;
    const float* wir = W_ih + h * Hh;
    const float* wiz = W_ih + (Hh + h) * Hh;
    const float* win = W_ih + (2 * Hh + h) * Hh;
    const float* whr = W_hh + h * Hh;
    const float* whz = W_hh + (Hh + h) * Hh;
    const float* whn = W_hh + (2 * Hh + h) * Hh;
    float gir = b_ih[h], giz = b_ih[Hh + h], gin = b_ih[2 * Hh + h];
    float ghr = b_hh[h], ghz = b_hh[Hh + h], ghn = b_hh[2 * Hh + h];
    for (int k = 0; k < Hh; ++k) {
        float a = sr[k] * inv;
        float xv = xr[k];
        gir += a * wir[k];
        giz += a * wiz[k];
        gin += a * win[k];
        ghr += xv * whr[k];
        ghz += xv * whz[k];
        ghn += xv * whn[k];
    }
    float r = sigf(gir + ghr);
    float z = sigf(giz + ghz);
    float nn = tanhfast(gin + r * ghn);
    xout[idx] = (1.0f - z) * nn + z * xr[h];
}

// hi[n,h] = x[n,:]@Wa1[h,0:96] + ba1[h];  hj[n,h] = x[n,:]@Wa1[h,96:192]
__global__ __launch_bounds__(256) void hihj_kernel(
    const float* __restrict__ x, const float* __restrict__ Wa1,
    const float* __restrict__ ba1,
    float* __restrict__ hi, float* __restrict__ hj)
{
    int idx = blockIdx.x * 256 + threadIdx.x;
    if (idx >= NH) return;
    int n = idx / Hh, h = idx - n * Hh;
    const float* xr = x + n * Hh;
    const float* w = Wa1 + h * (2 * Hh);
    float a = 0.0f, bb = 0.0f;
    for (int k = 0; k < Hh; ++k) {
        float xv = xr[k];
        a += xv * w[k];
        bb += xv * w[Hh + k];
    }
    hi[idx] = a + ba1[h];
    hj[idx] = bb;
}

// Fused attention: per row i, compact j's with adj==1, compute
// c_j = sigmoid(sum_k sigmoid(hi[i,k]+hj[j,k]) * Wa2[k] + ba2), then
// xout[i,:] = sum_j c_j * x[j,:]
__global__ __launch_bounds__(256) void attn_kernel(
    const float* __restrict__ x, const float* __restrict__ hi,
    const float* __restrict__ hj, const float* __restrict__ Wa2,
    const float* __restrict__ ba2, const int* __restrict__ adj,
    float* __restrict__ xout)
{
    __shared__ __align__(16) float hi_s[Hh];
    __shared__ __align__(16) float wa2_s[Hh];
    __shared__ int jlist[Nn];
    __shared__ float clist[Nn];
    __shared__ int cnt_s;
    int i = blockIdx.x;
    int tid = threadIdx.x;
    if (tid == 0) cnt_s = 0;
    if (tid < Hh) {
        hi_s[tid] = hi[i * Hh + tid];
        wa2_s[tid] = Wa2[tid];
    }
    __syncthreads();
    // phase 0: compact active columns
    const int* arow = adj + i * Nn;
    for (int j = tid; j < Nn; j += 256) {
        if (arow[j] == 1) {
            int p = atomicAdd(&cnt_s, 1);
            jlist[p] = j;
        }
    }
    __syncthreads();
    int cnt = cnt_s;
    float b2 = ba2[0];
    // phase 1: coefficients (transcendental-bound inner loop, float4 loads)
    for (int idx = tid; idx < cnt; idx += 256) {
        int j = jlist[idx];
        const float4* hj4 = (const float4*)(hj + j * Hh);
        const float4* hi4 = (const float4*)hi_s;
        const float4* w4 = (const float4*)wa2_s;
        float ssum = 0.0f;
#pragma unroll
        for (int k4 = 0; k4 < Hh / 4; ++k4) {
            float4 a = hj4[k4];
            float4 b = hi4[k4];
            float4 w = w4[k4];
            ssum += sigf(a.x + b.x) * w.x;
            ssum += sigf(a.y + b.y) * w.y;
            ssum += sigf(a.z + b.z) * w.z;
            ssum += sigf(a.w + b.w) * w.w;
        }
        clist[idx] = sigf(ssum + b2);
    }
    __syncthreads();
    // phase 2: xout[i,h] = sum_idx clist[idx] * x[jlist[idx], h]
    if (tid < Hh) {
        float acc = 0.0f;
        for (int idx = 0; idx < cnt; ++idx) {
            acc += clist[idx] * x[jlist[idx] * Hh + tid];
        }
        xout[i * Hh + tid] = acc;
    }
}

// out1[n] = sigmoid(x@Wp1 + bp1); out2[n] = sigmoid(x@Wp2 + bp2)
__global__ __launch_bounds__(256) void out_kernel(
    const float* __restrict__ x,
    const float* __restrict__ Wp1, const float* __restrict__ bp1,
    const float* __restrict__ Wp2, const float* __restrict__ bp2,
    float* __restrict__ out)
{
    int n = blockIdx.x * 256 + threadIdx.x;
    if (n >= Nn) return;
    const float* xr = x + n * Hh;
    float a = 0.0f, b = 0.0f;
    for (int k = 0; k < Hh; ++k) {
        a += xr[k] * Wp1[k];
        b += xr[k] * Wp2[k];
    }
    out[n] = sigf(a + bp1[0]);
    out[Nn + n] = sigf(b + bp2[0]);
}

extern "C" void kernel_launch(void* const* d_in, const int* in_sizes, int n_in,
                              void* d_out, int out_size, void* d_ws, size_t ws_size,
                              hipStream_t stream)
{
    const float* x_in   = (const float*)d_in[0];
    const int*   ei     = (const int*)d_in[1];   // (2, E) int
    const int*   adj    = (const int*)d_in[2];   // (N, N) int
    const float* W_init = (const float*)d_in[3];
    const float* b_init = (const float*)d_in[4];
    const float* W_ggc  = (const float*)d_in[5];
    const float* W_ih   = (const float*)d_in[6];
    const float* W_hh   = (const float*)d_in[7];
    const float* b_ih   = (const float*)d_in[8];
    const float* b_hh   = (const float*)d_in[9];
    const float* Wa1    = (const float*)d_in[10];
    const float* ba1    = (const float*)d_in[11];
    const float* Wa2    = (const float*)d_in[12];
    const float* ba2    = (const float*)d_in[13];
    const float* Wo1    = (const float*)d_in[14];
    const float* bo1    = (const float*)d_in[15];
    const float* Wo2    = (const float*)d_in[16];
    const float* bo2    = (const float*)d_in[17];
    const float* Wp1    = (const float*)d_in[18];
    const float* bp1    = (const float*)d_in[19];
    const float* Wp2    = (const float*)d_in[20];
    const float* bp2    = (const float*)d_in[21];
    float* out = (float*)d_out;

    // workspace layout (floats); total ~ 8*NH + N  ~= 3.2 MB
    float* ws  = (float*)d_ws;
    float* xA  = ws;            // (N,H) current x
    float* xB  = ws + NH;       // (N,H) post-GRU x
    float* m   = ws + 2 * NH;   // (N,H) messages
    float* s   = ws + 3 * NH;   // (N,H) segment sum
    float* hi  = ws + 4 * NH;   // (N,H)
    float* hj  = ws + 5 * NH;   // (N,H)
    float* cnt = ws + 6 * NH;   // (N)
    float* t1  = ws + 6 * NH + Nn;
    float* t2  = t1 + NH;

    const int nhBlocks = (NH + 255) / 256;

    // x = leaky(x[:, :9] @ W_init.T + b_init)
    lin_kernel<1, 0><<<nhBlocks, 256, 0, stream>>>(x_in, W_init, b_init, xA,
                                                   Nn, IN_K, Hh, IN_STRIDE);

    for (int u = 0; u < 2; ++u) {
        // m = x @ W_ggc
        lin_kernel<0, 1><<<nhBlocks, 256, 0, stream>>>(xA, W_ggc, nullptr, m,
                                                       Nn, Hh, Hh, Hh);
        zero2_kernel<<<nhBlocks, 256, 0, stream>>>(s, NH, cnt, Nn);
        scatter_kernel<<<(Ee * Hh + 255) / 256, 256, 0, stream>>>(m, ei, s, cnt);
        gru_kernel<<<nhBlocks, 256, 0, stream>>>(xA, s, cnt, W_ih, W_hh,
                                                 b_ih, b_hh, xB);
        hihj_kernel<<<nhBlocks, 256, 0, stream>>>(xB, Wa1, ba1, hi, hj);
        attn_kernel<<<Nn, 256, 0, stream>>>(xB, hi, hj, Wa2, ba2, adj, xA);
    }

    // final head
    lin_kernel<1, 0><<<nhBlocks, 256, 0, stream>>>(xA, Wo1, bo1, t1, Nn, Hh, Hh, Hh);
    lin_kernel<1, 0><<<nhBlocks, 256, 0, stream>>>(t1, Wo2, bo2, t2, Nn, Hh, Hh, Hh);
    out_kernel<<<(Nn + 255) / 256, 256, 0, stream>>>(t2, Wp1, bp1, Wp2, bp2, out);
}

// Round 2
// 472.681 us; speedup vs baseline: 1.1889x; 1.1889x over previous
//
#include <hip/hip_runtime.h>
#include <hip/hip_bf16.h>

// Problem constants (from reference)
#define Nn 1024
#define Hh 96
#define Ee 16384
#define IN_K 9       // IN_RAW-1
#define IN_STRIDE 10 // x is (N, 10), we use first 9 cols
#define NH (Nn * Hh)

__device__ __forceinline__ float sigf(float v) {
    return __builtin_amdgcn_rcpf(1.0f + __expf(-v));
}
__device__ __forceinline__ float tanhfast(float v) {
    float e = __expf(2.0f * v);
    return (e - 1.0f) * __builtin_amdgcn_rcpf(e + 1.0f);
}
__device__ __forceinline__ float leakyf(float v) {
    return v >= 0.0f ? v : 0.01f * v;
}

// -------------------------------------------------------------------------
// Transpose all stride-pathological weights into Wt[k][col] layout so the
// per-(n,h) dot loops read coalesced (stride-1 across lanes).
//   Wt_ih [k*288+c] = W_ih[c*96+k]   (288x96 -> 96x288)
//   Wt_hh [k*288+c] = W_hh[c*96+k]
//   Wt_a1i[k*96+h]  = Wa1[h*192+k]        (Wa1[:, :96])
//   Wt_a1j[k*96+h]  = Wa1[h*192+96+k]     (Wa1[:, 96:])
//   Wt_o1 [k*96+j]  = Wo1[j*96+k]
//   Wt_o2 [k*96+j]  = Wo2[j*96+k]
// total 92160 elements
__global__ __launch_bounds__(256) void transpose_all_kernel(
    const float* __restrict__ W_ih, const float* __restrict__ W_hh,
    const float* __restrict__ Wa1, const float* __restrict__ Wo1,
    const float* __restrict__ Wo2,
    float* __restrict__ Wt_ih, float* __restrict__ Wt_hh,
    float* __restrict__ Wt_a1i, float* __restrict__ Wt_a1j,
    float* __restrict__ Wt_o1, float* __restrict__ Wt_o2)
{
    int idx = blockIdx.x * 256 + threadIdx.x;
    if (idx < 27648) {
        int k = idx / 288, c = idx % 288;
        Wt_ih[idx] = W_ih[c * 96 + k];
        return;
    }
    idx -= 27648;
    if (idx < 27648) {
        int k = idx / 288, c = idx % 288;
        Wt_hh[idx] = W_hh[c * 96 + k];
        return;
    }
    idx -= 27648;
    if (idx < 9216) {
        int k = idx / 96, h = idx % 96;
        Wt_a1i[idx] = Wa1[h * 192 + k];
        return;
    }
    idx -= 9216;
    if (idx < 9216) {
        int k = idx / 96, h = idx % 96;
        Wt_a1j[idx] = Wa1[h * 192 + 96 + k];
        return;
    }
    idx -= 9216;
    if (idx < 9216) {
        int k = idx / 96, j = idx % 96;
        Wt_o1[idx] = Wo1[j * 96 + k];
        return;
    }
    idx -= 9216;
    if (idx < 9216) {
        int k = idx / 96, j = idx % 96;
        Wt_o2[idx] = Wo2[j * 96 + k];
    }
}

// Generic linear with Wt[k][h_out] (coalesced): out[n,j] = act(in[n,:]@Wt + b)
template <int ACT>
__global__ __launch_bounds__(256) void lin_kernel(
    const float* __restrict__ in, const float* __restrict__ Wt,
    const float* __restrict__ b, float* __restrict__ out,
    int n_rows, int h_in, int h_out, int in_stride)
{
    int idx = blockIdx.x * 256 + threadIdx.x;
    if (idx >= n_rows * h_out) return;
    int n = idx / h_out, j = idx - n * h_out;
    const float* xr = in + n * in_stride;
    float acc = b ? b[j] : 0.0f;
    const float* w = Wt + j;
    for (int k = 0; k < h_in; ++k) acc += xr[k] * w[k * h_out];
    if (ACT == 1) acc = leakyf(acc);
    out[idx] = acc;
}

// init linear: W_init stored (96, 9) row-major; tiny, keep gather form
__global__ __launch_bounds__(256) void init_lin_kernel(
    const float* __restrict__ in, const float* __restrict__ W,
    const float* __restrict__ b, float* __restrict__ out)
{
    int idx = blockIdx.x * 256 + threadIdx.x;
    if (idx >= NH) return;
    int n = idx / Hh, j = idx - n * Hh;
    const float* xr = in + n * IN_STRIDE;
    const float* wr = W + j * IN_K;
    float acc = b[j];
#pragma unroll
    for (int k = 0; k < IN_K; ++k) acc += xr[k] * wr[k];
    out[idx] = leakyf(acc);
}

__global__ __launch_bounds__(256) void zero2_kernel(float* a, int na, float* b, int nb)
{
    int i = blockIdx.x * 256 + threadIdx.x;
    if (i < na) a[i] = 0.0f;
    if (i < nb) b[i] = 0.0f;
}

// scatter-add: s[tgt[e], h] += m[src[e], h]; cnt[tgt[e]] += 1
__global__ __launch_bounds__(256) void scatter_kernel(
    const float* __restrict__ m, const int* __restrict__ ei,
    float* __restrict__ s, float* __restrict__ cnt)
{
    int idx = blockIdx.x * 256 + threadIdx.x;
    if (idx >= Ee * Hh) return;
    int e = idx / Hh, h = idx - e * Hh;
    int src = ei[e];
    int tgt = ei[Ee + e];
    atomicAdd(&s[tgt * Hh + h], m[src * Hh + h]);
    if (h == 0) atomicAdd(&cnt[tgt], 1.0f);
}

// GRU cell with transposed weights Wt_ih/Wt_hh (96 x 288, [k][c]):
// coalesced weight reads, broadcast x/s reads.
__global__ __launch_bounds__(256) void gru_kernel(
    const float* __restrict__ x, const float* __restrict__ s,
    const float* __restrict__ cnt,
    const float* __restrict__ Wt_ih, const float* __restrict__ Wt_hh,
    const float* __restrict__ b_ih, const float* __restrict__ b_hh,
    float* __restrict__ xout)
{
    int idx = blockIdx.x * 256 + threadIdx.x;
    if (idx >= NH) return;
    int n = idx / Hh, h = idx - n * Hh;
    float inv = __builtin_amdgcn_rcpf(fmaxf(cnt[n], 1.0f));
    const float* xr = x + n * Hh;
    const float* sr = s + n * Hh;
    const float* pih = Wt_ih + h;
    const float* phh = Wt_hh + h;
    float gir = b_ih[h], giz = b_ih[Hh + h], gin = b_ih[2 * Hh + h];
    float ghr = b_hh[h], ghz = b_hh[Hh + h], ghn = b_hh[2 * Hh + h];
    for (int k = 0; k < Hh; ++k) {
        float a = sr[k] * inv;
        float xv = xr[k];
        int o = k * 288;
        gir += a * pih[o];
        giz += a * pih[o + 96];
        gin += a * pih[o + 192];
        ghr += xv * phh[o];
        ghz += xv * phh[o + 96];
        ghn += xv * phh[o + 192];
    }
    float r = sigf(gir + ghr);
    float z = sigf(giz + ghz);
    float nn = tanhfast(gin + r * ghn);
    xout[idx] = (1.0f - z) * nn + z * xr[h];
}

// hi[n,h] = x[n,:]@Wa1[h,0:96] + ba1[h];  hj[n,h] = x[n,:]@Wa1[h,96:192]
// using transposed Wt_a1i/Wt_a1j (96x96, [k][h]) -> coalesced
__global__ __launch_bounds__(256) void hihj_kernel(
    const float* __restrict__ x, const float* __restrict__ Wt_a1i,
    const float* __restrict__ Wt_a1j, const float* __restrict__ ba1,
    float* __restrict__ hi, float* __restrict__ hj)
{
    int idx = blockIdx.x * 256 + threadIdx.x;
    if (idx >= NH) return;
    int n = idx / Hh, h = idx - n * Hh;
    const float* xr = x + n * Hh;
    const float* wi = Wt_a1i + h;
    const float* wj = Wt_a1j + h;
    float a = 0.0f, bb = 0.0f;
    for (int k = 0; k < Hh; ++k) {
        float xv = xr[k];
        a += xv * wi[k * 96];
        bb += xv * wj[k * 96];
    }
    hi[idx] = a + ba1[h];
    hj[idx] = bb;
}

// Fused attention: per row i, compact j's with adj==1, compute
// c_j = sigmoid(sum_k sigmoid(hi[i,k]+hj[j,k]) * Wa2[k] + ba2), then
// xout[i,:] = sum_j c_j * x[j,:]
__global__ __launch_bounds__(256) void attn_kernel(
    const float* __restrict__ x, const float* __restrict__ hi,
    const float* __restrict__ hj, const float* __restrict__ Wa2,
    const float* __restrict__ ba2, const int* __restrict__ adj,
    float* __restrict__ xout)
{
    __shared__ __align__(16) float hi_s[Hh];
    __shared__ __align__(16) float wa2_s[Hh];
    __shared__ int jlist[Nn];
    __shared__ float clist[Nn];
    __shared__ float part[Hh];
    __shared__ int cnt_s;
    int i = blockIdx.x;
    int tid = threadIdx.x;
    if (tid == 0) cnt_s = 0;
    if (tid < Hh) {
        hi_s[tid] = hi[i * Hh + tid];
        wa2_s[tid] = Wa2[tid];
    }
    __syncthreads();
    // phase 0: compact active columns
    const int* arow = adj + i * Nn;
    for (int j = tid; j < Nn; j += 256) {
        if (arow[j] == 1) {
            int p = atomicAdd(&cnt_s, 1);
            jlist[p] = j;
        }
    }
    __syncthreads();
    int cnt = cnt_s;
    float b2 = ba2[0];
    // phase 1: coefficients (transcendental-bound, float4 loads)
    for (int idx = tid; idx < cnt; idx += 256) {
        int j = jlist[idx];
        const float4* hj4 = (const float4*)(hj + j * Hh);
        const float4* hi4 = (const float4*)hi_s;
        const float4* w4 = (const float4*)wa2_s;
        float ssum = 0.0f;
#pragma unroll
        for (int k4 = 0; k4 < Hh / 4; ++k4) {
            float4 a = hj4[k4];
            float4 b = hi4[k4];
            float4 w = w4[k4];
            ssum += sigf(a.x + b.x) * w.x;
            ssum += sigf(a.y + b.y) * w.y;
            ssum += sigf(a.z + b.z) * w.z;
            ssum += sigf(a.w + b.w) * w.w;
        }
        clist[idx] = sigf(ssum + b2);
    }
    __syncthreads();
    // phase 2: xout[i,h] = sum_idx clist[idx] * x[jlist[idx], h]
    // split j-range across 2 groups of 96 lanes, LDS-combine
    int c = tid / Hh;          // 0,1 active; 2 idle
    int h = tid - c * Hh;
    float acc = 0.0f;
    if (c < 2) {
        for (int idx = c; idx < cnt; idx += 2) {
            acc += clist[idx] * x[jlist[idx] * Hh + h];
        }
    }
    if (c == 1) part[h] = acc;
    __syncthreads();
    if (c == 0) xout[i * Hh + h] = acc + part[h];
}

// out1[n] = sigmoid(x@Wp1 + bp1); out2[n] = sigmoid(x@Wp2 + bp2)
__global__ __launch_bounds__(256) void out_kernel(
    const float* __restrict__ x,
    const float* __restrict__ Wp1, const float* __restrict__ bp1,
    const float* __restrict__ Wp2, const float* __restrict__ bp2,
    float* __restrict__ out)
{
    int n = blockIdx.x * 256 + threadIdx.x;
    if (n >= Nn) return;
    const float* xr = x + n * Hh;
    float a = 0.0f, b = 0.0f;
    for (int k = 0; k < Hh; ++k) {
        a += xr[k] * Wp1[k];
        b += xr[k] * Wp2[k];
    }
    out[n] = sigf(a + bp1[0]);
    out[Nn + n] = sigf(b + bp2[0]);
}

extern "C" void kernel_launch(void* const* d_in, const int* in_sizes, int n_in,
                              void* d_out, int out_size, void* d_ws, size_t ws_size,
                              hipStream_t stream)
{
    const float* x_in   = (const float*)d_in[0];
    const int*   ei     = (const int*)d_in[1];   // (2, E) int
    const int*   adj    = (const int*)d_in[2];   // (N, N) int
    const float* W_init = (const float*)d_in[3];
    const float* b_init = (const float*)d_in[4];
    const float* W_ggc  = (const float*)d_in[5]; // (96,96) [k][j] already coalesced
    const float* W_ih   = (const float*)d_in[6];
    const float* W_hh   = (const float*)d_in[7];
    const float* b_ih   = (const float*)d_in[8];
    const float* b_hh   = (const float*)d_in[9];
    const float* Wa1    = (const float*)d_in[10];
    const float* ba1    = (const float*)d_in[11];
    const float* Wa2    = (const float*)d_in[12];
    const float* ba2    = (const float*)d_in[13];
    const float* Wo1    = (const float*)d_in[14];
    const float* bo1    = (const float*)d_in[15];
    const float* Wo2    = (const float*)d_in[16];
    const float* bo2    = (const float*)d_in[17];
    const float* Wp1    = (const float*)d_in[18];
    const float* bp1    = (const float*)d_in[19];
    const float* Wp2    = (const float*)d_in[20];
    const float* bp2    = (const float*)d_in[21];
    float* out = (float*)d_out;

    // workspace layout (floats): 8*NH + N + transposed weights ~= 3.5 MB
    float* ws   = (float*)d_ws;
    float* xA   = ws;            // (N,H) current x
    float* xB   = ws + NH;       // (N,H) post-GRU x
    float* m    = ws + 2 * NH;   // (N,H) messages
    float* s    = ws + 3 * NH;   // (N,H) segment sum
    float* hi   = ws + 4 * NH;   // (N,H)
    float* hj   = ws + 5 * NH;   // (N,H)
    float* cnt  = ws + 6 * NH;   // (N)
    float* t1   = ws + 6 * NH + Nn;
    float* t2   = t1 + NH;
    float* Wt_ih  = t2 + NH;         // 96*288
    float* Wt_hh  = Wt_ih + 27648;   // 96*288
    float* Wt_a1i = Wt_hh + 27648;   // 96*96
    float* Wt_a1j = Wt_a1i + 9216;   // 96*96
    float* Wt_o1  = Wt_a1j + 9216;   // 96*96
    float* Wt_o2  = Wt_o1 + 9216;    // 96*96

    const int nhBlocks = (NH + 255) / 256;

    transpose_all_kernel<<<(92160 + 255) / 256, 256, 0, stream>>>(
        W_ih, W_hh, Wa1, Wo1, Wo2, Wt_ih, Wt_hh, Wt_a1i, Wt_a1j, Wt_o1, Wt_o2);

    // x = leaky(x[:, :9] @ W_init.T + b_init)
    init_lin_kernel<<<nhBlocks, 256, 0, stream>>>(x_in, W_init, b_init, xA);

    for (int u = 0; u < 2; ++u) {
        // m = x @ W_ggc   (W_ggc already [k][j] layout)
        lin_kernel<0><<<nhBlocks, 256, 0, stream>>>(xA, W_ggc, nullptr, m,
                                                    Nn, Hh, Hh, Hh);
        zero2_kernel<<<nhBlocks, 256, 0, stream>>>(s, NH, cnt, Nn);
        scatter_kernel<<<(Ee * Hh + 255) / 256, 256, 0, stream>>>(m, ei, s, cnt);
        gru_kernel<<<nhBlocks, 256, 0, stream>>>(xA, s, cnt, Wt_ih, Wt_hh,
                                                 b_ih, b_hh, xB);
        hihj_kernel<<<nhBlocks, 256, 0, stream>>>(xB, Wt_a1i, Wt_a1j, ba1, hi, hj);
        attn_kernel<<<Nn, 256, 0, stream>>>(xB, hi, hj, Wa2, ba2, adj, xA);
    }

    // final head (transposed weights -> coalesced)
    lin_kernel<1><<<nhBlocks, 256, 0, stream>>>(xA, Wt_o1, bo1, t1, Nn, Hh, Hh, Hh);
    lin_kernel<1><<<nhBlocks, 256, 0, stream>>>(t1, Wt_o2, bo2, t2, Nn, Hh, Hh, Hh);
    out_kernel<<<(Nn + 255) / 256, 256, 0, stream>>>(t2, Wp1, bp1, Wp2, bp2, out);
}

// Round 3
// 421.069 us; speedup vs baseline: 1.3346x; 1.1226x over previous
//
#include <hip/hip_runtime.h>
#include <hip/hip_bf16.h>

// Problem constants (from reference)
#define Nn 1024
#define Hh 96
#define Ee 16384
#define IN_K 9       // IN_RAW-1
#define IN_STRIDE 10 // x is (N, 10), we use first 9 cols
#define NH (Nn * Hh)

__device__ __forceinline__ float sigf(float v) {
    return __builtin_amdgcn_rcpf(1.0f + __expf(-v));
}
__device__ __forceinline__ float tanhfast(float v) {
    float e = __expf(2.0f * v);
    return (e - 1.0f) * __builtin_amdgcn_rcpf(e + 1.0f);
}
__device__ __forceinline__ float leakyf(float v) {
    return v >= 0.0f ? v : 0.01f * v;
}

// -------------------------------------------------------------------------
// Transpose stride-pathological weights into Wt[k][col] layout (coalesced).
__global__ __launch_bounds__(256) void transpose_all_kernel(
    const float* __restrict__ W_ih, const float* __restrict__ W_hh,
    const float* __restrict__ Wa1, const float* __restrict__ Wo1,
    const float* __restrict__ Wo2,
    float* __restrict__ Wt_ih, float* __restrict__ Wt_hh,
    float* __restrict__ Wt_a1i, float* __restrict__ Wt_a1j,
    float* __restrict__ Wt_o1, float* __restrict__ Wt_o2)
{
    int idx = blockIdx.x * 256 + threadIdx.x;
    if (idx < 27648) {
        int k = idx / 288, c = idx % 288;
        Wt_ih[idx] = W_ih[c * 96 + k];
        return;
    }
    idx -= 27648;
    if (idx < 27648) {
        int k = idx / 288, c = idx % 288;
        Wt_hh[idx] = W_hh[c * 96 + k];
        return;
    }
    idx -= 27648;
    if (idx < 9216) {
        int k = idx / 96, h = idx % 96;
        Wt_a1i[idx] = Wa1[h * 192 + k];
        return;
    }
    idx -= 9216;
    if (idx < 9216) {
        int k = idx / 96, h = idx % 96;
        Wt_a1j[idx] = Wa1[h * 192 + 96 + k];
        return;
    }
    idx -= 9216;
    if (idx < 9216) {
        int k = idx / 96, j = idx % 96;
        Wt_o1[idx] = Wo1[j * 96 + k];
        return;
    }
    idx -= 9216;
    if (idx < 9216) {
        int k = idx / 96, j = idx % 96;
        Wt_o2[idx] = Wo2[j * 96 + k];
    }
}

// zero A_edge (1024x1024) and cnt (1024), float4 stores
__global__ __launch_bounds__(256) void zeroA_kernel(float* __restrict__ A,
                                                    float* __restrict__ cnt)
{
    int i = blockIdx.x * 256 + threadIdx.x;
    if (i < (Nn * Nn) / 4) ((float4*)A)[i] = make_float4(0.f, 0.f, 0.f, 0.f);
    if (i < Nn) cnt[i] = 0.0f;
}

// A_edge[tgt][src] += 1 (handles duplicate edges); cnt[tgt] += 1
__global__ __launch_bounds__(256) void edges_kernel(const int* __restrict__ ei,
                                                    float* __restrict__ A,
                                                    float* __restrict__ cnt)
{
    int e = blockIdx.x * 256 + threadIdx.x;
    if (e >= Ee) return;
    int src = ei[e];
    int tgt = ei[Ee + e];
    atomicAdd(&A[tgt * Nn + src], 1.0f);
    atomicAdd(&cnt[tgt], 1.0f);
}

// Generic linear with Wt[k][h_out] (coalesced): out[n,j] = act(in[n,:]@Wt + b)
template <int ACT>
__global__ __launch_bounds__(256) void lin_kernel(
    const float* __restrict__ in, const float* __restrict__ Wt,
    const float* __restrict__ b, float* __restrict__ out,
    int n_rows, int h_in, int h_out, int in_stride)
{
    int idx = blockIdx.x * 256 + threadIdx.x;
    if (idx >= n_rows * h_out) return;
    int n = idx / h_out, j = idx - n * h_out;
    const float* xr = in + n * in_stride;
    float acc = b ? b[j] : 0.0f;
    const float* w = Wt + j;
    for (int k = 0; k < h_in; ++k) acc += xr[k] * w[k * h_out];
    if (ACT == 1) acc = leakyf(acc);
    out[idx] = acc;
}

// init linear: W_init stored (96, 9) row-major; tiny, keep gather form
__global__ __launch_bounds__(256) void init_lin_kernel(
    const float* __restrict__ in, const float* __restrict__ W,
    const float* __restrict__ b, float* __restrict__ out)
{
    int idx = blockIdx.x * 256 + threadIdx.x;
    if (idx >= NH) return;
    int n = idx / Hh, j = idx - n * Hh;
    const float* xr = in + n * IN_STRIDE;
    const float* wr = W + j * IN_K;
    float acc = b[j];
#pragma unroll
    for (int k = 0; k < IN_K; ++k) acc += xr[k] * wr[k];
    out[idx] = leakyf(acc);
}

// Dense fp32 GEMM: out[n,h] = sum_k A[n,k] * X[k,h]
// A: (Nn, Nn) row-major, X: (Nn, Hh) row-major, out: (Nn, Hh)
// thread = (n,h); A reads broadcast (96 lanes share row), X reads coalesced.
__global__ __launch_bounds__(256) void gemm_kernel(
    const float* __restrict__ A, const float* __restrict__ X,
    float* __restrict__ out)
{
    int idx = blockIdx.x * 256 + threadIdx.x;
    if (idx >= NH) return;
    int n = idx / Hh, h = idx - n * Hh;
    const float4* a4 = (const float4*)(A + n * Nn);
    const float* xc = X + h;
    float acc = 0.0f;
#pragma unroll 4
    for (int k4 = 0; k4 < Nn / 4; ++k4) {
        float4 a = a4[k4];
        int k = k4 * 4;
        acc += a.x * xc[k * Hh];
        acc += a.y * xc[(k + 1) * Hh];
        acc += a.z * xc[(k + 2) * Hh];
        acc += a.w * xc[(k + 3) * Hh];
    }
    out[idx] = acc;
}

// GRU cell with transposed weights Wt_ih/Wt_hh (96 x 288, [k][c])
__global__ __launch_bounds__(256) void gru_kernel(
    const float* __restrict__ x, const float* __restrict__ s,
    const float* __restrict__ cnt,
    const float* __restrict__ Wt_ih, const float* __restrict__ Wt_hh,
    const float* __restrict__ b_ih, const float* __restrict__ b_hh,
    float* __restrict__ xout)
{
    int idx = blockIdx.x * 256 + threadIdx.x;
    if (idx >= NH) return;
    int n = idx / Hh, h = idx - n * Hh;
    float inv = __builtin_amdgcn_rcpf(fmaxf(cnt[n], 1.0f));
    const float* xr = x + n * Hh;
    const float* sr = s + n * Hh;
    const float* pih = Wt_ih + h;
    const float* phh = Wt_hh + h;
    float gir = b_ih[h], giz = b_ih[Hh + h], gin = b_ih[2 * Hh + h];
    float ghr = b_hh[h], ghz = b_hh[Hh + h], ghn = b_hh[2 * Hh + h];
    for (int k = 0; k < Hh; ++k) {
        float a = sr[k] * inv;
        float xv = xr[k];
        int o = k * 288;
        gir += a * pih[o];
        giz += a * pih[o + 96];
        gin += a * pih[o + 192];
        ghr += xv * phh[o];
        ghz += xv * phh[o + 96];
        ghn += xv * phh[o + 192];
    }
    float r = sigf(gir + ghr);
    float z = sigf(giz + ghz);
    float nn = tanhfast(gin + r * ghn);
    xout[idx] = (1.0f - z) * nn + z * xr[h];
}

// hi[n,h] = x[n,:]@Wa1[:, :96].T + ba1[h]   (ba1 folded here)
// hj[n,h] = x[n,:]@Wa1[:, 96:].T            (raw; exp applied in transpose)
__global__ __launch_bounds__(256) void hihj_kernel(
    const float* __restrict__ x, const float* __restrict__ Wt_a1i,
    const float* __restrict__ Wt_a1j, const float* __restrict__ ba1,
    float* __restrict__ hi, float* __restrict__ hj)
{
    int idx = blockIdx.x * 256 + threadIdx.x;
    if (idx >= NH) return;
    int n = idx / Hh, h = idx - n * Hh;
    const float* xr = x + n * Hh;
    const float* wi = Wt_a1i + h;
    const float* wj = Wt_a1j + h;
    float a = 0.0f, bb = 0.0f;
    for (int k = 0; k < Hh; ++k) {
        float xv = xr[k];
        a += xv * wi[k * 96];
        bb += xv * wj[k * 96];
    }
    hi[idx] = a + ba1[h];
    hj[idx] = bb;
}

// EjT[k][j] = exp(-hj[j][k]) — tiled transpose + exp, 32x32 tiles, padded LDS
__global__ __launch_bounds__(256) void texp_kernel(
    const float* __restrict__ hj, float* __restrict__ EjT)
{
    __shared__ float tile[32][33];
    int jt = blockIdx.x * 32;  // j tile base
    int kt = blockIdx.y * 32;  // k tile base (96 -> 3 tiles)
    int tx = threadIdx.x & 31;
    int ty0 = threadIdx.x >> 5; // 0..7
    for (int ty = ty0; ty < 32; ty += 8)
        tile[ty][tx] = hj[(jt + ty) * Hh + kt + tx];
    __syncthreads();
    for (int ty = ty0; ty < 32; ty += 8)
        EjT[(kt + ty) * Nn + jt + tx] = __expf(-tile[tx][ty]);
}

// Dense masked coefficients:
// C[i][j] = adj[i][j]==1 ? sigmoid( sum_k rcp(1 + Ei[k]*EjT[k][j]) * Wa2[k] + ba2 ) : 0
// One block per i; each thread owns 4 consecutive j (float4 loads of EjT).
__global__ __launch_bounds__(256) void coeffs_kernel(
    const float* __restrict__ hi, const float* __restrict__ EjT,
    const float* __restrict__ Wa2, const float* __restrict__ ba2,
    const int* __restrict__ adj, float* __restrict__ C)
{
    __shared__ __align__(16) float eis[Hh];
    __shared__ __align__(16) float ws_[Hh];
    int i = blockIdx.x;
    int tid = threadIdx.x;
    if (tid < Hh) {
        eis[tid] = __expf(-hi[i * Hh + tid]);
        ws_[tid] = Wa2[tid];
    }
    __syncthreads();
    int j0 = tid * 4;
    float s0 = 0.f, s1 = 0.f, s2 = 0.f, s3 = 0.f;
#pragma unroll 4
    for (int k = 0; k < Hh; ++k) {
        float4 e4 = *(const float4*)(EjT + k * Nn + j0);
        float eik = eis[k];
        float wk = ws_[k];
        s0 += __builtin_amdgcn_rcpf(fmaf(eik, e4.x, 1.0f)) * wk;
        s1 += __builtin_amdgcn_rcpf(fmaf(eik, e4.y, 1.0f)) * wk;
        s2 += __builtin_amdgcn_rcpf(fmaf(eik, e4.z, 1.0f)) * wk;
        s3 += __builtin_amdgcn_rcpf(fmaf(eik, e4.w, 1.0f)) * wk;
    }
    float b2 = ba2[0];
    int4 mk = *(const int4*)(adj + i * Nn + j0);
    float4 c;
    c.x = (mk.x == 1) ? sigf(s0 + b2) : 0.0f;
    c.y = (mk.y == 1) ? sigf(s1 + b2) : 0.0f;
    c.z = (mk.z == 1) ? sigf(s2 + b2) : 0.0f;
    c.w = (mk.w == 1) ? sigf(s3 + b2) : 0.0f;
    *(float4*)(C + i * Nn + j0) = c;
}

// out1[n] = sigmoid(x@Wp1 + bp1); out2[n] = sigmoid(x@Wp2 + bp2)
__global__ __launch_bounds__(256) void out_kernel(
    const float* __restrict__ x,
    const float* __restrict__ Wp1, const float* __restrict__ bp1,
    const float* __restrict__ Wp2, const float* __restrict__ bp2,
    float* __restrict__ out)
{
    int n = blockIdx.x * 256 + threadIdx.x;
    if (n >= Nn) return;
    const float* xr = x + n * Hh;
    float a = 0.0f, b = 0.0f;
    for (int k = 0; k < Hh; ++k) {
        a += xr[k] * Wp1[k];
        b += xr[k] * Wp2[k];
    }
    out[n] = sigf(a + bp1[0]);
    out[Nn + n] = sigf(b + bp2[0]);
}

extern "C" void kernel_launch(void* const* d_in, const int* in_sizes, int n_in,
                              void* d_out, int out_size, void* d_ws, size_t ws_size,
                              hipStream_t stream)
{
    const float* x_in   = (const float*)d_in[0];
    const int*   ei     = (const int*)d_in[1];   // (2, E)
    const int*   adj    = (const int*)d_in[2];   // (N, N)
    const float* W_init = (const float*)d_in[3];
    const float* b_init = (const float*)d_in[4];
    const float* W_ggc  = (const float*)d_in[5]; // (96,96) [k][j] already coalesced
    const float* W_ih   = (const float*)d_in[6];
    const float* W_hh   = (const float*)d_in[7];
    const float* b_ih   = (const float*)d_in[8];
    const float* b_hh   = (const float*)d_in[9];
    const float* Wa1    = (const float*)d_in[10];
    const float* ba1    = (const float*)d_in[11];
    const float* Wa2    = (const float*)d_in[12];
    const float* ba2    = (const float*)d_in[13];
    const float* Wo1    = (const float*)d_in[14];
    const float* bo1    = (const float*)d_in[15];
    const float* Wo2    = (const float*)d_in[16];
    const float* bo2    = (const float*)d_in[17];
    const float* Wp1    = (const float*)d_in[18];
    const float* bp1    = (const float*)d_in[19];
    const float* Wp2    = (const float*)d_in[20];
    const float* bp2    = (const float*)d_in[21];
    float* out = (float*)d_out;

    // workspace layout (floats), total ~12.3 MB
    float* ws   = (float*)d_ws;
    float* xA   = ws;             // (N,H)
    float* xB   = xA + NH;        // (N,H)
    float* m    = xB + NH;        // (N,H)
    float* s    = m + NH;         // (N,H)
    float* hi   = s + NH;         // (N,H)
    float* hj   = hi + NH;        // (N,H)
    float* t1   = hj + NH;        // (N,H)
    float* t2   = t1 + NH;        // (N,H)
    float* EjT  = t2 + NH;        // (H,N) transposed exp(-hj)
    float* cnt  = EjT + NH;       // (N)
    float* Wt_ih  = cnt + Nn;         // 96*288
    float* Wt_hh  = Wt_ih + 27648;    // 96*288
    float* Wt_a1i = Wt_hh + 27648;    // 96*96
    float* Wt_a1j = Wt_a1i + 9216;    // 96*96
    float* Wt_o1  = Wt_a1j + 9216;    // 96*96
    float* Wt_o2  = Wt_o1 + 9216;     // 96*96
    float* A_edge = Wt_o2 + 9216;     // (N,N)
    float* C      = A_edge + Nn * Nn; // (N,N)

    const int nhBlocks = (NH + 255) / 256;

    transpose_all_kernel<<<(92160 + 255) / 256, 256, 0, stream>>>(
        W_ih, W_hh, Wa1, Wo1, Wo2, Wt_ih, Wt_hh, Wt_a1i, Wt_a1j, Wt_o1, Wt_o2);

    // adjacency-from-edges matrix + in-degree counts (once; x-independent)
    zeroA_kernel<<<(Nn * Nn / 4 + 255) / 256, 256, 0, stream>>>(A_edge, cnt);
    edges_kernel<<<(Ee + 255) / 256, 256, 0, stream>>>(ei, A_edge, cnt);

    // x = leaky(x[:, :9] @ W_init.T + b_init)
    init_lin_kernel<<<nhBlocks, 256, 0, stream>>>(x_in, W_init, b_init, xA);

    for (int u = 0; u < 2; ++u) {
        // m = x @ W_ggc
        lin_kernel<0><<<nhBlocks, 256, 0, stream>>>(xA, W_ggc, nullptr, m,
                                                    Nn, Hh, Hh, Hh);
        // s = A_edge @ m   (replaces 1.5M-atomic scatter)
        gemm_kernel<<<nhBlocks, 256, 0, stream>>>(A_edge, m, s);
        gru_kernel<<<nhBlocks, 256, 0, stream>>>(xA, s, cnt, Wt_ih, Wt_hh,
                                                 b_ih, b_hh, xB);
        hihj_kernel<<<nhBlocks, 256, 0, stream>>>(xB, Wt_a1i, Wt_a1j, ba1, hi, hj);
        texp_kernel<<<dim3(Nn / 32, Hh / 32), 256, 0, stream>>>(hj, EjT);
        coeffs_kernel<<<Nn, 256, 0, stream>>>(hi, EjT, Wa2, ba2, adj, C);
        // x = C @ xB
        gemm_kernel<<<nhBlocks, 256, 0, stream>>>(C, xB, xA);
    }

    // final head (transposed weights -> coalesced)
    lin_kernel<1><<<nhBlocks, 256, 0, stream>>>(xA, Wt_o1, bo1, t1, Nn, Hh, Hh, Hh);
    lin_kernel<1><<<nhBlocks, 256, 0, stream>>>(t1, Wt_o2, bo2, t2, Nn, Hh, Hh, Hh);
    out_kernel<<<(Nn + 255) / 256, 256, 0, stream>>>(t2, Wp1, bp1, Wp2, bp2, out);
}

// Round 4
// 288.847 us; speedup vs baseline: 1.9455x; 1.4578x over previous
//
#include <hip/hip_runtime.h>
#include <hip/hip_bf16.h>

// Problem constants (from reference)
#define Nn 1024
#define Hh 96
#define Ee 16384
#define IN_K 9       // IN_RAW-1
#define IN_STRIDE 10 // x is (N, 10), we use first 9 cols
#define NH (Nn * Hh)
#define XS 128       // padded row stride for x-like (N,96) buffers
#define KSLICES 8
#define SLICE 128    // 1024 / KSLICES

__device__ __forceinline__ float sigf(float v) {
    return __builtin_amdgcn_rcpf(1.0f + __expf(-v));
}
__device__ __forceinline__ float tanhfast(float v) {
    float e = __expf(2.0f * v);
    return (e - 1.0f) * __builtin_amdgcn_rcpf(e + 1.0f);
}
__device__ __forceinline__ float leakyf(float v) {
    return v >= 0.0f ? v : 0.01f * v;
}

// -------------------------------------------------------------------------
// One-time: transpose stride-pathological weights into Wt[k][col] layouts.
__global__ __launch_bounds__(256) void transpose_all_kernel(
    const float* __restrict__ W_ih, const float* __restrict__ W_hh,
    const float* __restrict__ Wa1, const float* __restrict__ Wo1,
    const float* __restrict__ Wo2,
    float* __restrict__ Wt_ih, float* __restrict__ Wt_hh,
    float* __restrict__ Wt_a1i, float* __restrict__ Wt_a1j,
    float* __restrict__ Wt_o1, float* __restrict__ Wt_o2)
{
    int idx = blockIdx.x * 256 + threadIdx.x;
    if (idx < 27648) {
        int k = idx / 288, c = idx % 288;
        Wt_ih[idx] = W_ih[c * 96 + k];
        return;
    }
    idx -= 27648;
    if (idx < 27648) {
        int k = idx / 288, c = idx % 288;
        Wt_hh[idx] = W_hh[c * 96 + k];
        return;
    }
    idx -= 27648;
    if (idx < 9216) {
        int k = idx / 96, h = idx % 96;
        Wt_a1i[idx] = Wa1[h * 192 + k];
        return;
    }
    idx -= 9216;
    if (idx < 9216) {
        int k = idx / 96, h = idx % 96;
        Wt_a1j[idx] = Wa1[h * 192 + 96 + k];
        return;
    }
    idx -= 9216;
    if (idx < 9216) {
        int k = idx / 96, j = idx % 96;
        Wt_o1[idx] = Wo1[j * 96 + k];
        return;
    }
    idx -= 9216;
    if (idx < 9216) {
        int k = idx / 96, j = idx % 96;
        Wt_o2[idx] = Wo2[j * 96 + k];
    }
}

// One-time: Wf[k][c] = sum_j W_ggc[k][j] * W_ih[c][j]  (96 x 288)
// (associativity: gi = (A@x/cnt) @ Wf, eliminating the m = x@W_ggc pass)
__global__ __launch_bounds__(256) void wf_kernel(
    const float* __restrict__ W_ggc, const float* __restrict__ Wt_ih,
    float* __restrict__ Wf)
{
    int idx = blockIdx.x * 256 + threadIdx.x;
    if (idx >= 96 * 288) return;
    int k = idx / 288, c = idx % 288;
    const float* g = W_ggc + k * 96;
    const float* w = Wt_ih + c;
    float acc = 0.0f;
    for (int j = 0; j < 96; ++j) acc += g[j] * w[j * 288];
    Wf[idx] = acc;
}

// zero A_edge (1024x1024) and cnt (1024)
__global__ __launch_bounds__(256) void zeroA_kernel(float* __restrict__ A,
                                                    float* __restrict__ cnt)
{
    int i = blockIdx.x * 256 + threadIdx.x;
    if (i < (Nn * Nn) / 4) ((float4*)A)[i] = make_float4(0.f, 0.f, 0.f, 0.f);
    if (i < Nn) cnt[i] = 0.0f;
}

// A_edge[tgt][src] += 1 (handles duplicate edges); cnt[tgt] += 1
__global__ __launch_bounds__(256) void edges_kernel(const int* __restrict__ ei,
                                                    float* __restrict__ A,
                                                    float* __restrict__ cnt)
{
    int e = blockIdx.x * 256 + threadIdx.x;
    if (e >= Ee) return;
    int src = ei[e];
    int tgt = ei[Ee + e];
    atomicAdd(&A[tgt * Nn + src], 1.0f);
    atomicAdd(&cnt[tgt], 1.0f);
}

// init linear: xA[n*XS + j] = leaky(x[n,:9] @ W_init[j,:] + b_init[j])
__global__ __launch_bounds__(256) void init_lin_kernel(
    const float* __restrict__ in, const float* __restrict__ W,
    const float* __restrict__ b, float* __restrict__ out)
{
    int idx = blockIdx.x * 256 + threadIdx.x;
    if (idx >= NH) return;
    int n = idx / Hh, j = idx - n * Hh;
    const float* xr = in + n * IN_STRIDE;
    const float* wr = W + j * IN_K;
    float acc = b[j];
#pragma unroll
    for (int k = 0; k < IN_K; ++k) acc += xr[k] * wr[k];
    out[n * XS + j] = leakyf(acc);
}

// Blocked fp32 GEMM with split-k: partial[s][n][h] = sum_{k in slice s} A[n,k]*X[k,h]
// A: (1024,1024) row-major. X: (1024, XS=128) padded row-major (only h<96 valid).
// Block = 256 threads: hg = tid%32 (4 cols each, covers 128 padded cols),
// nl = tid/32 (8 rows). Grid = (128 n-tiles, KSLICES).
// X row for each k is read once per block (512B, broadcast across nl) -> 67MB L2.
__global__ __launch_bounds__(256) void gemm_kernel(
    const float* __restrict__ A, const float* __restrict__ X,
    float* __restrict__ partial)
{
    int tid = threadIdx.x;
    int hg = tid & 31;
    int nl = tid >> 5;
    int n = blockIdx.x * 8 + nl;
    int k0 = blockIdx.y * SLICE;
    int h4 = hg * 4;
    const float* arow = A + n * Nn + k0;
    const float* xp = X + k0 * XS + h4;
    float4 acc = make_float4(0.f, 0.f, 0.f, 0.f);
#pragma unroll 4
    for (int kk = 0; kk < SLICE; kk += 4) {
        float4 a4 = *(const float4*)(arow + kk);
        float4 x0 = *(const float4*)(xp + (kk + 0) * XS);
        float4 x1 = *(const float4*)(xp + (kk + 1) * XS);
        float4 x2 = *(const float4*)(xp + (kk + 2) * XS);
        float4 x3 = *(const float4*)(xp + (kk + 3) * XS);
        acc.x += a4.x * x0.x; acc.y += a4.x * x0.y; acc.z += a4.x * x0.z; acc.w += a4.x * x0.w;
        acc.x += a4.y * x1.x; acc.y += a4.y * x1.y; acc.z += a4.y * x1.z; acc.w += a4.y * x1.w;
        acc.x += a4.z * x2.x; acc.y += a4.z * x2.y; acc.z += a4.z * x2.z; acc.w += a4.z * x2.w;
        acc.x += a4.w * x3.x; acc.y += a4.w * x3.y; acc.z += a4.w * x3.z; acc.w += a4.w * x3.w;
    }
    *(float4*)(partial + (blockIdx.y * Nn + n) * XS + h4) = acc;
}

// Reduce KSLICES partials. SCALE=1: multiply by 1/max(cnt[n],1), write stride 96 (P).
// SCALE=0: plain sum, write stride XS (next xA).
template <int SCALE, int OSTRIDE>
__global__ __launch_bounds__(256) void reduce_kernel(
    const float* __restrict__ partial, const float* __restrict__ cnt,
    float* __restrict__ out)
{
    int idx = blockIdx.x * 256 + threadIdx.x;
    if (idx >= NH) return;
    int n = idx / Hh, h = idx - n * Hh;
    const float* p = partial + n * XS + h;
    float acc = 0.0f;
#pragma unroll
    for (int s = 0; s < KSLICES; ++s) acc += p[s * (Nn * XS)];
    if (SCALE) acc *= __builtin_amdgcn_rcpf(fmaxf(cnt[n], 1.0f));
    out[n * OSTRIDE + h] = acc;
}

// Fused GRU + attention-projection + exp kernel.
// Block = 384 threads = 4 full rows (r = tid/96, h = tid%96).
// Inputs: xA (stride XS), P = (A@xA)/cnt (stride 96), Wf (96x288), Wt_hh (96x288).
// Step 1 (GRU): xB[n,h]; stage row in LDS.
// Step 2: hi = xB@Wa1[:,:96].T + ba1 -> Ei = exp(-hi)   (stride 96)
//         hj = xB@Wa1[:,96:].T      -> EjT[h][n] = exp(-hj)  (transposed)
__global__ __launch_bounds__(384) void gru_fused_kernel(
    const float* __restrict__ x, const float* __restrict__ P,
    const float* __restrict__ Wf, const float* __restrict__ Wt_hh,
    const float* __restrict__ b_ih, const float* __restrict__ b_hh,
    const float* __restrict__ Wt_a1i, const float* __restrict__ Wt_a1j,
    const float* __restrict__ ba1,
    float* __restrict__ xB, float* __restrict__ Ei, float* __restrict__ EjT)
{
    __shared__ float xs[4][Hh];
    int tid = threadIdx.x;
    int r = tid / Hh, h = tid - r * Hh;
    int n = blockIdx.x * 4 + r;
    const float* xr = x + n * XS;
    const float* pr = P + n * Hh;
    const float* pf = Wf + h;
    const float* ph = Wt_hh + h;
    float gir = b_ih[h], giz = b_ih[Hh + h], gin = b_ih[2 * Hh + h];
    float ghr = b_hh[h], ghz = b_hh[Hh + h], ghn = b_hh[2 * Hh + h];
    for (int k = 0; k < Hh; ++k) {
        float a = pr[k];
        float xv = xr[k];
        int o = k * 288;
        gir += a * pf[o];
        giz += a * pf[o + 96];
        gin += a * pf[o + 192];
        ghr += xv * ph[o];
        ghz += xv * ph[o + 96];
        ghn += xv * ph[o + 192];
    }
    float rr = sigf(gir + ghr);
    float z = sigf(giz + ghz);
    float nn = tanhfast(gin + rr * ghn);
    float xo = (1.0f - z) * nn + z * xr[h];
    xB[n * XS + h] = xo;
    xs[r][h] = xo;
    __syncthreads();
    // attention projections from LDS row
    const float* wi = Wt_a1i + h;
    const float* wj = Wt_a1j + h;
    const float* row = xs[r];
    float a = 0.0f, bb = 0.0f;
    for (int k = 0; k < Hh; ++k) {
        float xv = row[k];
        a += xv * wi[k * 96];
        bb += xv * wj[k * 96];
    }
    Ei[n * Hh + h] = __expf(-(a + ba1[h]));
    EjT[h * Nn + n] = __expf(-bb);
}

// Dense masked coefficients:
// C[i][j] = adj==1 ? sigmoid( sum_k rcp(1 + Ei[i,k]*EjT[k][j]) * Wa2[k] + ba2 ) : 0
__global__ __launch_bounds__(256) void coeffs_kernel(
    const float* __restrict__ Ei, const float* __restrict__ EjT,
    const float* __restrict__ Wa2, const float* __restrict__ ba2,
    const int* __restrict__ adj, float* __restrict__ C)
{
    __shared__ __align__(16) float eis[Hh];
    __shared__ __align__(16) float ws_[Hh];
    int i = blockIdx.x;
    int tid = threadIdx.x;
    if (tid < Hh) {
        eis[tid] = Ei[i * Hh + tid];
        ws_[tid] = Wa2[tid];
    }
    __syncthreads();
    int j0 = tid * 4;
    float s0 = 0.f, s1 = 0.f, s2 = 0.f, s3 = 0.f;
#pragma unroll 4
    for (int k = 0; k < Hh; ++k) {
        float4 e4 = *(const float4*)(EjT + k * Nn + j0);
        float eik = eis[k];
        float wk = ws_[k];
        s0 += __builtin_amdgcn_rcpf(fmaf(eik, e4.x, 1.0f)) * wk;
        s1 += __builtin_amdgcn_rcpf(fmaf(eik, e4.y, 1.0f)) * wk;
        s2 += __builtin_amdgcn_rcpf(fmaf(eik, e4.z, 1.0f)) * wk;
        s3 += __builtin_amdgcn_rcpf(fmaf(eik, e4.w, 1.0f)) * wk;
    }
    float b2 = ba2[0];
    int4 mk = *(const int4*)(adj + i * Nn + j0);
    float4 c;
    c.x = (mk.x == 1) ? sigf(s0 + b2) : 0.0f;
    c.y = (mk.y == 1) ? sigf(s1 + b2) : 0.0f;
    c.z = (mk.z == 1) ? sigf(s2 + b2) : 0.0f;
    c.w = (mk.w == 1) ? sigf(s3 + b2) : 0.0f;
    *(float4*)(C + i * Nn + j0) = c;
}

// head linear: out[n*96+j] = leaky(in[n,:]@Wt[:,j] + b[j]); in stride = ISTRIDE
template <int ISTRIDE>
__global__ __launch_bounds__(256) void lin_kernel(
    const float* __restrict__ in, const float* __restrict__ Wt,
    const float* __restrict__ b, float* __restrict__ out)
{
    int idx = blockIdx.x * 256 + threadIdx.x;
    if (idx >= NH) return;
    int n = idx / Hh, j = idx - n * Hh;
    const float* xr = in + n * ISTRIDE;
    const float* w = Wt + j;
    float acc = b[j];
    for (int k = 0; k < Hh; ++k) acc += xr[k] * w[k * 96];
    out[n * Hh + j] = leakyf(acc);
}

// out1[n] = sigmoid(x@Wp1 + bp1); out2[n] = sigmoid(x@Wp2 + bp2)
__global__ __launch_bounds__(256) void out_kernel(
    const float* __restrict__ x,
    const float* __restrict__ Wp1, const float* __restrict__ bp1,
    const float* __restrict__ Wp2, const float* __restrict__ bp2,
    float* __restrict__ out)
{
    int n = blockIdx.x * 256 + threadIdx.x;
    if (n >= Nn) return;
    const float* xr = x + n * Hh;
    float a = 0.0f, b = 0.0f;
    for (int k = 0; k < Hh; ++k) {
        a += xr[k] * Wp1[k];
        b += xr[k] * Wp2[k];
    }
    out[n] = sigf(a + bp1[0]);
    out[Nn + n] = sigf(b + bp2[0]);
}

extern "C" void kernel_launch(void* const* d_in, const int* in_sizes, int n_in,
                              void* d_out, int out_size, void* d_ws, size_t ws_size,
                              hipStream_t stream)
{
    const float* x_in   = (const float*)d_in[0];
    const int*   ei     = (const int*)d_in[1];
    const int*   adj    = (const int*)d_in[2];
    const float* W_init = (const float*)d_in[3];
    const float* b_init = (const float*)d_in[4];
    const float* W_ggc  = (const float*)d_in[5];
    const float* W_ih   = (const float*)d_in[6];
    const float* W_hh   = (const float*)d_in[7];
    const float* b_ih   = (const float*)d_in[8];
    const float* b_hh   = (const float*)d_in[9];
    const float* Wa1    = (const float*)d_in[10];
    const float* ba1    = (const float*)d_in[11];
    const float* Wa2    = (const float*)d_in[12];
    const float* ba2    = (const float*)d_in[13];
    const float* Wo1    = (const float*)d_in[14];
    const float* bo1    = (const float*)d_in[15];
    const float* Wo2    = (const float*)d_in[16];
    const float* bo2    = (const float*)d_in[17];
    const float* Wp1    = (const float*)d_in[18];
    const float* bp1    = (const float*)d_in[19];
    const float* Wp2    = (const float*)d_in[20];
    const float* bp2    = (const float*)d_in[21];
    float* out = (float*)d_out;

    // workspace layout (floats), ~15.5 MB
    float* ws      = (float*)d_ws;
    float* xA      = ws;                    // (N, XS)
    float* xB      = xA + Nn * XS;          // (N, XS)
    float* P       = xB + Nn * XS;          // (N, 96)  (A@x)/cnt
    float* Ei      = P + NH;                // (N, 96)  exp(-hi)
    float* EjT     = Ei + NH;               // (96, N)  exp(-hj) transposed
    float* t1      = EjT + NH;              // (N, 96)
    float* t2      = t1 + NH;               // (N, 96)
    float* cnt     = t2 + NH;               // (N)
    float* partial = cnt + Nn;              // (KSLICES, N, XS) = 4 MB
    float* A_edge  = partial + KSLICES * Nn * XS;  // (N, N)
    float* C       = A_edge + Nn * Nn;             // (N, N)
    float* Wt_ih   = C + Nn * Nn;           // 96*288 (temp, for wf)
    float* Wt_hh   = Wt_ih + 27648;
    float* Wf      = Wt_hh + 27648;         // 96*288
    float* Wt_a1i  = Wf + 27648;
    float* Wt_a1j  = Wt_a1i + 9216;
    float* Wt_o1   = Wt_a1j + 9216;
    float* Wt_o2   = Wt_o1 + 9216;

    const int nhBlocks = (NH + 255) / 256;
    const dim3 gemmGrid(Nn / 8, KSLICES);

    // one-time setup
    transpose_all_kernel<<<(92160 + 255) / 256, 256, 0, stream>>>(
        W_ih, W_hh, Wa1, Wo1, Wo2, Wt_ih, Wt_hh, Wt_a1i, Wt_a1j, Wt_o1, Wt_o2);
    wf_kernel<<<(27648 + 255) / 256, 256, 0, stream>>>(W_ggc, Wt_ih, Wf);
    zeroA_kernel<<<(Nn * Nn / 4 + 255) / 256, 256, 0, stream>>>(A_edge, cnt);
    edges_kernel<<<(Ee + 255) / 256, 256, 0, stream>>>(ei, A_edge, cnt);
    init_lin_kernel<<<nhBlocks, 256, 0, stream>>>(x_in, W_init, b_init, xA);

    for (int u = 0; u < 2; ++u) {
        // P = (A_edge @ xA) / cnt   (message pass; W_ggc/W_ih folded into Wf)
        gemm_kernel<<<gemmGrid, 256, 0, stream>>>(A_edge, xA, partial);
        reduce_kernel<1, Hh><<<nhBlocks, 256, 0, stream>>>(partial, cnt, P);
        // GRU + attention projections + exps (fused)
        gru_fused_kernel<<<Nn / 4, 384, 0, stream>>>(
            xA, P, Wf, Wt_hh, b_ih, b_hh, Wt_a1i, Wt_a1j, ba1, xB, Ei, EjT);
        // attention coefficients (dense masked)
        coeffs_kernel<<<Nn, 256, 0, stream>>>(Ei, EjT, Wa2, ba2, adj, C);
        // xA = C @ xB
        gemm_kernel<<<gemmGrid, 256, 0, stream>>>(C, xB, partial);
        reduce_kernel<0, XS><<<nhBlocks, 256, 0, stream>>>(partial, cnt, xA);
    }

    // final head
    lin_kernel<XS><<<nhBlocks, 256, 0, stream>>>(xA, Wt_o1, bo1, t1);
    lin_kernel<Hh><<<nhBlocks, 256, 0, stream>>>(t1, Wt_o2, bo2, t2);
    out_kernel<<<(Nn + 255) / 256, 256, 0, stream>>>(t2, Wp1, bp1, Wp2, bp2, out);
}